// Round 12
// baseline (230.215 us; speedup 1.0000x reference)
//
#include <hip/hip_runtime.h>
#include <hip/hip_bf16.h>
#include <math.h>

// GNNLayer: B=4,T=4096,D=128,H=4,DH=32,FF=256
// bf16 MFMA (16x16x32) everywhere, fp32 accum, fp32 LN/residual/bias.
// R12: revert R11 split-K (occupancy proven irrelevant; merge cost 5us).
//      Theory: attn is L2-BW-bound (~23 TB/s; R9/R10/R11 invariance, no pipe
//      saturated). Fixes:
//      (1) k_attn: per-group __syncthreads keeps 4 waves in lockstep so their
//          IDENTICAL K/V tile reads hit L1 -> ~4x L2 traffic cut. One line.
//      (2) k_ff1: erff GELU (OCML ~25 insts) -> tanh-form x*t/(t+1), t=__expf
//          (max dev 3e-4 << threshold).
//      (3) k_knorm: 16 -> 256 blocks (was using 16 of 256 CUs).
//      (4) k_pack: scalar byte loads -> uint4 vector loads.

#define B_ 4
#define T_ 4096
#define D_ 128
#define H_ 4
#define DH_ 32
#define FF_ 256
#define M_ (B_*T_)

typedef unsigned short u16;
typedef __attribute__((ext_vector_type(8))) short bf16x8;
typedef __attribute__((ext_vector_type(4))) float f32x4;
typedef __attribute__((ext_vector_type(4))) u16 u16x4;

// ---- workspace layout (bytes, 256-aligned) ----
constexpr size_t OFF_FLAG  = 0;     // int flag @0, float kmax2[16] @64
constexpr size_t OFF_MASKW = 256;                      // u32[T][T/32] = 2 MB
constexpr size_t OFF_XB    = OFF_MASKW + 2097152;      // bf16 x        4 MB
constexpr size_t OFF_WQKVT = OFF_XB    + 4194304;      // bf16 [384][128]
constexpr size_t OFF_WOT   = OFF_WQKVT + 98304;        // bf16 [128][128]
constexpr size_t OFF_W1T   = OFF_WOT   + 32768;        // bf16 [256][128]
constexpr size_t OFF_W2T   = OFF_W1T   + 65536;        // bf16 [128][256]
constexpr size_t OFF_QW    = OFF_W2T   + 65536;        // bf16 [16][T][32] (q, pre-scaled 1/sqrt(DH))
constexpr size_t OFF_KW    = OFF_QW    + 4194304;      // bf16 [16][T*32] fragment-major
constexpr size_t OFF_VT    = OFF_KW    + 4194304;      // bf16 [16][T*32] fragment-major v^T
constexpr size_t OFF_AO    = OFF_VT    + 4194304;      // bf16 attn out [M][128]
constexpr size_t OFF_Y32   = OFF_AO    + 4194304;      // f32 y (post-LN1) [M][128]
constexpr size_t OFF_YB    = OFF_Y32   + 8388608;      // bf16 y
constexpr size_t OFF_HB    = OFF_YB    + 4194304;      // bf16 gelu(ff1) [M][256]

__device__ __forceinline__ u16 f2bf(float f){
  unsigned u = __float_as_uint(f);
  u += 0x7FFFu + ((u >> 16) & 1u);
  return (u16)(u >> 16);
}

__device__ __forceinline__ float bf2f(u16 b){
  return __uint_as_float((unsigned)b << 16);
}

// frag loader (row-major source): p = base + row*stride + k0 + 4*(lane>>4)
__device__ __forceinline__ bf16x8 load_frag(const u16* p){
  union { bf16x8 v; uint2 u[2]; } f;
  f.u[0] = *(const uint2*)(p);
  f.u[1] = *(const uint2*)(p + 16);
  return f.v;
}

// ---- mask dtype detection + kmax2 zeroing ----
__global__ void k_detect(const unsigned* m, int* flag, float* kmax2){
  if (threadIdx.x < 16) kmax2[threadIdx.x] = 0.f;
  __shared__ int s_i32, s_f32;
  if (threadIdx.x == 0){ s_i32 = 1; s_f32 = 1; }
  __syncthreads();
  int li = 1, lf = 1;
  for (int i = threadIdx.x; i < 16384; i += 256){
    unsigned w = m[i];
    li &= (w <= 1u);
    lf &= (w == 0u || w == 0x3F800000u);
  }
  if (!li) atomicAnd(&s_i32, 0);
  if (!lf) atomicAnd(&s_f32, 0);
  __syncthreads();
  if (threadIdx.x == 0) *flag = (s_i32 | s_f32);
}

// pack (adj | eye) into bits: mw[i*128 + j/32] bit (j%32). Vectorized loads.
__global__ void k_pack(const void* mask, const int* flag, unsigned* mw){
  int idx = blockIdx.x*256 + threadIdx.x;   // word index, T*T/32 total
  int i = idx >> 7, wj = idx & 127;
  unsigned w = 0;
  if (*flag){
    // 4-byte elements: 32 dwords = 8 x uint4
    const uint4* p = (const uint4*)((const unsigned*)mask + (size_t)i*T_ + wj*32);
    #pragma unroll
    for (int j = 0; j < 8; j++){
      uint4 v = p[j];
      w |= (unsigned)(v.x != 0u) << (4*j);
      w |= (unsigned)(v.y != 0u) << (4*j + 1);
      w |= (unsigned)(v.z != 0u) << (4*j + 2);
      w |= (unsigned)(v.w != 0u) << (4*j + 3);
    }
  } else {
    // 1-byte elements: 32 bytes = 2 x uint4
    const uint4* p = (const uint4*)((const unsigned char*)mask + (size_t)i*T_ + wj*32);
    uint4 a = p[0], b = p[1];
    const unsigned dw[8] = { a.x, a.y, a.z, a.w, b.x, b.y, b.z, b.w };
    #pragma unroll
    for (int j = 0; j < 8; j++){
      unsigned d = dw[j];
      w |= (unsigned)((d & 0x000000FFu) != 0u) << (4*j);
      w |= (unsigned)((d & 0x0000FF00u) != 0u) << (4*j + 1);
      w |= (unsigned)((d & 0x00FF0000u) != 0u) << (4*j + 2);
      w |= (unsigned)((d & 0xFF000000u) != 0u) << (4*j + 3);
    }
  }
  if ((i >> 5) == wj) w |= 1u << (i & 31);
  mw[idx] = w;
}

__global__ void k_conv_x(const float* x, u16* xb){
  int i = (blockIdx.x*256 + threadIdx.x)*4;
  float4 v = *(const float4*)(x + i);
  u16x4 o = { f2bf(v.x), f2bf(v.y), f2bf(v.z), f2bf(v.w) };
  *(u16x4*)(xb + i) = o;
}

// weights -> bf16, transposed [N][K]
__global__ void k_conv_w(const float* Wq, const float* Wk, const float* Wv, const float* Wo,
                         const float* W1, const float* W2,
                         u16* wqkvt, u16* wot, u16* w1t, u16* w2t){
  int idx = blockIdx.x*256 + threadIdx.x;
  if (idx < 49152){                      // wqkvt[n<384][k<128]
    int n = idx >> 7, k = idx & 127;
    float v = (n < 128) ? Wq[k*128 + n] : (n < 256 ? Wk[k*128 + (n-128)] : Wv[k*128 + (n-256)]);
    wqkvt[idx] = f2bf(v);
  } else if (idx < 65536){               // wot[n<128][k<128]
    int j = idx - 49152, n = j >> 7, k = j & 127;
    wot[j] = f2bf(Wo[k*128 + n]);
  } else if (idx < 98304){               // w1t[n<256][k<128]
    int j = idx - 65536, n = j >> 7, k = j & 127;
    w1t[j] = f2bf(W1[k*256 + n]);
  } else if (idx < 131072){              // w2t[n<128][k<256]
    int j = idx - 98304, n = j >> 8, k = j & 255;
    w2t[j] = f2bf(W2[k*128 + n]);
  }
}

// QKV GEMM: grid 1024 (16 rows each), 4 waves x 96 cols. q scaled by 1/sqrt(32).
// K and V written in fragment-major layouts.
__global__ __launch_bounds__(256) void k_qkv(const u16* xb, const u16* wt,
    const float* bq, const float* bk, const float* bv,
    u16* qw, u16* kw, u16* vt){
  const int wv = threadIdx.x >> 6, lane = threadIdx.x & 63;
  const int r15 = lane & 15, g = lane >> 4;
  const int m0 = blockIdx.x * 16;
  f32x4 acc[6] = {};
  const u16* ar = xb + (size_t)(m0 + r15)*D_ + 4*g;
  #pragma unroll
  for (int kk = 0; kk < D_; kk += 32){
    bf16x8 af = load_frag(ar + kk);
    #pragma unroll
    for (int nf = 0; nf < 6; nf++){
      const u16* br = wt + (size_t)(wv*96 + nf*16 + r15)*D_ + kk + 4*g;
      acc[nf] = __builtin_amdgcn_mfma_f32_16x16x32_bf16(af, load_frag(br), acc[nf], 0, 0, 0);
    }
  }
  const int b = m0 >> 12, t0 = m0 & (T_-1);
  #pragma unroll
  for (int nf = 0; nf < 6; nf++){
    int ncol = wv*96 + nf*16 + r15;
    if (ncol < 128){
      int h = ncol >> 5, d = ncol & 31;
      float bias = bq[ncol];
      u16* dst = qw + ((size_t)(b*H_ + h)*T_)*DH_;
      #pragma unroll
      for (int rr = 0; rr < 4; rr++){
        int t = t0 + 4*g + rr;
        dst[(size_t)t*DH_ + d] = f2bf((acc[nf][rr] + bias) * 0.17677669529663687f);  // 1/sqrt(32)
      }
    } else if (ncol < 256){
      // K fragment-major: S_k(t,d) = (t>>4)*512 + ((d>>2)&3)*128 + (t&15)*8 + 4*(d>>4) + (d&3)
      int c = ncol - 128, h = c >> 5, d = c & 31;
      float bias = bk[c];
      u16* dst = kw + (size_t)(b*H_ + h)*T_*DH_
               + (size_t)(t0 >> 4)*512 + (size_t)((d >> 2) & 3)*128 + 4*(d >> 4) + (d & 3);
      #pragma unroll
      for (int rr = 0; rr < 4; rr++)
        dst[(4*g + rr)*8] = f2bf(acc[nf][rr] + bias);   // t&15 = 4g+rr
    } else {
      // V fragment-major: key t=t0+4g+rr, fixed d. base + rr are consecutive elems.
      int c = ncol - 256, h = c >> 5, d = c & 31;
      float bias = bv[c];
      int t = t0 + 4*g;
      int tin = t & 31;
      u16x4 v4;
      #pragma unroll
      for (int rr = 0; rr < 4; rr++) v4[rr] = f2bf(acc[nf][rr] + bias);
      u16* dst = vt + (size_t)(b*H_ + h)*T_*DH_
               + (size_t)(t >> 5)*1024 + (size_t)(d >> 4)*512
               + (size_t)(g*16 + (d & 15))*8 + 4*(tin >> 4);
      *(u16x4*)dst = v4;
    }
  }
}

// max_j ||k_j||^2 per (b,h) -> kmax2[bh]. Grid 256 (16 bh x 16 slices), 1 key/thread.
__global__ void k_knorm(const u16* kw, float* kmax2){
  const int bh = blockIdx.x >> 4, slice = blockIdx.x & 15;
  const int t = slice*256 + threadIdx.x;
  const u16* base = kw + (size_t)bh*T_*DH_ + (size_t)(t >> 4)*512 + (t & 15)*8;
  float s = 0.f;
  #pragma unroll
  for (int g = 0; g < 4; g++){
    union { uint4 u4; u16 e[8]; } v;
    v.u4 = *(const uint4*)(base + g*128);
    #pragma unroll
    for (int j = 0; j < 8; j++){ float f = bf2f(v.e[j]); s += f*f; }
  }
  float mx = s;
  #pragma unroll
  for (int d = 1; d < 64; d <<= 1) mx = fmaxf(mx, __shfl_xor(mx, d));
  if ((threadIdx.x & 63) == 0) atomicMax((unsigned*)(kmax2 + bh), __float_as_uint(mx));
}

// Bounded-softmax attention (__expf). Swapped QK^T; shift+mask in C-init;
// l via ones-column MFMA; pack via __float22bfloat162_rn. Per-group barrier
// keeps the block's 4 waves in lockstep so identical K/V reads hit L1.
// grid = BH(16) * T/64 = 1024; 4 waves/block, 16 queries/wave. XCD swizzle.
__global__ __launch_bounds__(256, 4) void k_attn12(const u16* qw, const u16* kw, const u16* vt,
    const unsigned* mw, const float* kmax2, u16* ao){
  const int wg = (blockIdx.x & 7)*128 + (blockIdx.x >> 3);   // 8 XCDs x 128 contiguous
  const int wv = threadIdx.x >> 6, lane = threadIdx.x & 63;
  const int r15 = lane & 15, g = lane >> 4;
  const int bh = wg >> 6;
  const int q0 = (wg & 63)*64 + wv*16;
  const u16* qp = qw + (size_t)bh*T_*DH_;
  const u16* kl = kw + (size_t)bh*T_*DH_ + lane*8;   // fragment-major, lane offset folded
  const u16* vl = vt + (size_t)bh*T_*DH_ + lane*8;
  const unsigned* mrow = mw + (size_t)(q0 + r15)*(T_/32);
  const bf16x8 qf = load_frag(qp + (size_t)(q0 + r15)*DH_ + 4*g);
  // ||q||^2 for this lane's query (q0+r15)
  float n0 = 0.f;
  #pragma unroll
  for (int j = 0; j < 8; j++){ float f = bf2f((u16)qf[j]); n0 += f*f; }
  n0 += __shfl_xor(n0, 16); n0 += __shfl_xor(n0, 32);
  const float bnd = sqrtf(n0 * kmax2[bh]) * 1.0001f + 1e-6f;  // >= max_j |q.k_j|
  union { u16 e[8]; bf16x8 v; } ones;
  #pragma unroll
  for (int j = 0; j < 8; j++) ones.e[j] = 0x3F80;
  f32x4 o0 = {}, o1 = {}, ol = {};
  for (int jb4 = 0; jb4 < T_; jb4 += 128){
    // lockstep: the block's 4 waves read the SAME K/V lines; bounding drift to
    // one 16KB group keeps them L1-resident (cuts L2 traffic ~4x)
    __syncthreads();
    const uint4 wv4 = *(const uint4*)(mrow + (jb4 >> 5));
    #pragma unroll
    for (int ji = 0; ji < 4; ji++){
      const int jb = jb4 + ji*32;
      const unsigned w = ((const unsigned*)&wv4)[ji];
      const unsigned u = w >> (4*g);
      bf16x8 kf0 = *(const bf16x8*)(kl + (size_t)(jb >> 4)*512);
      bf16x8 kf1 = *(const bf16x8*)(kl + (size_t)((jb >> 4) + 1)*512);
      bf16x8 vf0 = *(const bf16x8*)(vl + (size_t)(jb >> 5)*1024);
      bf16x8 vf1 = *(const bf16x8*)(vl + (size_t)(jb >> 5)*1024 + 512);
      f32x4 c0, c1;   // -bnd if masked-in else -1e30 (exp -> 0)
      #pragma unroll
      for (int rr = 0; rr < 4; rr++){
        c0[rr] = ((u >> rr) & 1u)        ? -bnd : -1e30f;
        c1[rr] = ((u >> (16 + rr)) & 1u) ? -bnd : -1e30f;
      }
      f32x4 s0 = __builtin_amdgcn_mfma_f32_16x16x32_bf16(kf0, qf, c0, 0, 0, 0);
      f32x4 s1 = __builtin_amdgcn_mfma_f32_16x16x32_bf16(kf1, qf, c1, 0, 0, 0);
      float p0[4], p1[4];
      #pragma unroll
      for (int rr = 0; rr < 4; rr++){
        p0[rr] = __expf(s0[rr]);
        p1[rr] = __expf(s1[rr]);
      }
      union { bf16x8 v; __hip_bfloat162 h2[4]; } pf;
      pf.h2[0] = __float22bfloat162_rn(make_float2(p0[0], p0[1]));
      pf.h2[1] = __float22bfloat162_rn(make_float2(p0[2], p0[3]));
      pf.h2[2] = __float22bfloat162_rn(make_float2(p1[0], p1[1]));
      pf.h2[3] = __float22bfloat162_rn(make_float2(p1[2], p1[3]));
      o0 = __builtin_amdgcn_mfma_f32_16x16x32_bf16(pf.v, vf0, o0, 0, 0, 0);
      o1 = __builtin_amdgcn_mfma_f32_16x16x32_bf16(pf.v, vf1, o1, 0, 0, 0);
      ol = __builtin_amdgcn_mfma_f32_16x16x32_bf16(pf.v, ones.v, ol, 0, 0, 0);
    }
  }
  const int b = bh >> 2, h = bh & 3;
  #pragma unroll
  for (int rr = 0; rr < 4; rr++){
    float li = ol[rr];                  // l for query 4g+rr, present in every lane
    float inv = li > 0.f ? 1.f/li : 0.f;
    size_t row = (size_t)(b*T_ + q0 + 4*g + rr)*D_;
    ao[row + h*DH_ + r15]      = f2bf(o0[rr]*inv);
    ao[row + h*DH_ + 16 + r15] = f2bf(o1[rr]*inv);
  }
}

// out-proj + residual + LN1. grid 256, 64 rows/block.
__global__ __launch_bounds__(256) void k_proj_ln1(const u16* ao, const u16* wot, const float* bo,
    const float* x, const float* g1, const float* be1, float* y32, u16* yb){
  const int wv = threadIdx.x >> 6, lane = threadIdx.x & 63;
  const int r15 = lane & 15, g = lane >> 4;
  const int m0 = blockIdx.x*64 + wv*16;
  f32x4 acc[8] = {};
  const u16* ar = ao + (size_t)(m0 + r15)*D_ + 4*g;
  #pragma unroll
  for (int kk = 0; kk < D_; kk += 32){
    bf16x8 af = load_frag(ar + kk);
    #pragma unroll
    for (int nf = 0; nf < 8; nf++)
      acc[nf] = __builtin_amdgcn_mfma_f32_16x16x32_bf16(af,
          load_frag(wot + (size_t)(nf*16 + r15)*D_ + kk + 4*g), acc[nf], 0, 0, 0);
  }
  #pragma unroll
  for (int rr = 0; rr < 4; rr++){
    const size_t m = m0 + 4*g + rr;
    float v[8], s1 = 0.f, s2 = 0.f;
    #pragma unroll
    for (int nf = 0; nf < 8; nf++){
      int col = nf*16 + r15;
      float t = acc[nf][rr] + bo[col] + x[m*D_ + col];
      v[nf] = t; s1 += t; s2 += t*t;
    }
    #pragma unroll
    for (int d = 1; d < 16; d <<= 1){ s1 += __shfl_xor(s1, d); s2 += __shfl_xor(s2, d); }
    float mu = s1 * (1.f/D_);
    float var = fmaxf(s2 * (1.f/D_) - mu*mu, 0.f);
    float inv = rsqrtf(var + 1e-5f);
    #pragma unroll
    for (int nf = 0; nf < 8; nf++){
      int col = nf*16 + r15;
      float o = (v[nf]-mu)*inv*g1[col] + be1[col];
      y32[m*D_ + col] = o;
      yb[m*D_ + col] = f2bf(o);
    }
  }
}

// FF1 + GELU (tanh form: x*t/(t+1), t=exp(2z), max dev 3e-4 from exact).
// grid 1024 (16 rows), 4 waves x 64 cols.
__global__ __launch_bounds__(256) void k_ff1(const u16* yb, const u16* w1t, const float* bf1, u16* hb){
  const int wv = threadIdx.x >> 6, lane = threadIdx.x & 63;
  const int r15 = lane & 15, g = lane >> 4;
  const int m0 = blockIdx.x*16;
  const int n0w = wv*64;
  f32x4 acc[4] = {};
  const u16* ar = yb + (size_t)(m0 + r15)*D_ + 4*g;
  #pragma unroll
  for (int kk = 0; kk < D_; kk += 32){
    bf16x8 af = load_frag(ar + kk);
    #pragma unroll
    for (int nf = 0; nf < 4; nf++)
      acc[nf] = __builtin_amdgcn_mfma_f32_16x16x32_bf16(af,
          load_frag(w1t + (size_t)(n0w + nf*16 + r15)*D_ + kk + 4*g), acc[nf], 0, 0, 0);
  }
  #pragma unroll
  for (int nf = 0; nf < 4; nf++){
    int col = n0w + nf*16 + r15;
    float bias = bf1[col];
    #pragma unroll
    for (int rr = 0; rr < 4; rr++){
      float vv = acc[nf][rr] + bias;
      // gelu(x) = 0.5x(1+tanh(z)) = x*t/(t+1), t=exp(2z), z=sqrt(2/pi)(x+0.044715x^3)
      float z2 = fminf(1.5957691216057308f*vv + 0.07135581778225507f*vv*vv*vv, 80.f);
      float t = __expf(z2);
      float gl = vv * t / (t + 1.f);
      hb[(size_t)(m0 + 4*g + rr)*FF_ + col] = f2bf(gl);
    }
  }
}

// FF2 + residual + LN2 -> d_out (fp32). grid 256, 64 rows/block.
__global__ __launch_bounds__(256) void k_ff2_ln2(const u16* hb, const u16* w2t, const float* b2,
    const float* y32, const float* g2, const float* be2, float* out){
  const int wv = threadIdx.x >> 6, lane = threadIdx.x & 63;
  const int r15 = lane & 15, g = lane >> 4;
  const int m0 = blockIdx.x*64 + wv*16;
  f32x4 acc[8] = {};
  const u16* ar = hb + (size_t)(m0 + r15)*FF_ + 4*g;
  #pragma unroll
  for (int kk = 0; kk < FF_; kk += 32){
    bf16x8 af = load_frag(ar + kk);
    #pragma unroll
    for (int nf = 0; nf < 8; nf++)
      acc[nf] = __builtin_amdgcn_mfma_f32_16x16x32_bf16(af,
          load_frag(w2t + (size_t)(nf*16 + r15)*FF_ + kk + 4*g), acc[nf], 0, 0, 0);
  }
  #pragma unroll
  for (int rr = 0; rr < 4; rr++){
    const size_t m = m0 + 4*g + rr;
    float v[8], s1 = 0.f, s2 = 0.f;
    #pragma unroll
    for (int nf = 0; nf < 8; nf++){
      int col = nf*16 + r15;
      float t = acc[nf][rr] + b2[col] + y32[m*D_ + col];
      v[nf] = t; s1 += t; s2 += t*t;
    }
    #pragma unroll
    for (int d = 1; d < 16; d <<= 1){ s1 += __shfl_xor(s1, d); s2 += __shfl_xor(s2, d); }
    float mu = s1 * (1.f/D_);
    float var = fmaxf(s2 * (1.f/D_) - mu*mu, 0.f);
    float inv = rsqrtf(var + 1e-5f);
    #pragma unroll
    for (int nf = 0; nf < 8; nf++){
      int col = nf*16 + r15;
      out[m*D_ + col] = (v[nf]-mu)*inv*g2[col] + be2[col];
    }
  }
}

extern "C" void kernel_launch(void* const* d_in, const int* in_sizes, int n_in,
                              void* d_out, int out_size, void* d_ws, size_t ws_size,
                              hipStream_t stream){
  const float* x   = (const float*)d_in[0];
  const void*  msk = d_in[1];
  const float* Wq = (const float*)d_in[2];  const float* bq  = (const float*)d_in[3];
  const float* Wk = (const float*)d_in[4];  const float* bk  = (const float*)d_in[5];
  const float* Wv = (const float*)d_in[6];  const float* bv  = (const float*)d_in[7];
  const float* Wo = (const float*)d_in[8];  const float* bo  = (const float*)d_in[9];
  const float* g1 = (const float*)d_in[10]; const float* be1 = (const float*)d_in[11];
  const float* W1 = (const float*)d_in[12]; const float* bf1 = (const float*)d_in[13];
  const float* W2 = (const float*)d_in[14]; const float* b2  = (const float*)d_in[15];
  const float* g2 = (const float*)d_in[16]; const float* be2 = (const float*)d_in[17];

  char* ws = (char*)d_ws;
  int*      flag  = (int*)     (ws + OFF_FLAG);
  float*    kmax2 = (float*)   (ws + OFF_FLAG + 64);
  unsigned* mw    = (unsigned*)(ws + OFF_MASKW);
  u16* xb    = (u16*)(ws + OFF_XB);
  u16* wqkvt = (u16*)(ws + OFF_WQKVT);
  u16* wot   = (u16*)(ws + OFF_WOT);
  u16* w1t   = (u16*)(ws + OFF_W1T);
  u16* w2t   = (u16*)(ws + OFF_W2T);
  u16* qw    = (u16*)(ws + OFF_QW);
  u16* kw    = (u16*)(ws + OFF_KW);
  u16* vt    = (u16*)(ws + OFF_VT);
  u16* ao    = (u16*)(ws + OFF_AO);
  float* y32 = (float*)(ws + OFF_Y32);
  u16* yb    = (u16*)(ws + OFF_YB);
  u16* hb    = (u16*)(ws + OFF_HB);

  k_detect<<<1, 256, 0, stream>>>((const unsigned*)msk, flag, kmax2);
  k_pack  <<<(T_*T_/32)/256, 256, 0, stream>>>(msk, flag, mw);
  k_conv_x<<<(M_*D_/4)/256, 256, 0, stream>>>(x, xb);
  k_conv_w<<<131072/256, 256, 0, stream>>>(Wq, Wk, Wv, Wo, W1, W2, wqkvt, wot, w1t, w2t);
  k_qkv   <<<M_/16, 256, 0, stream>>>(xb, wqkvt, bq, bk, bv, qw, kw, vt);
  k_knorm <<<(B_*H_)*16, 256, 0, stream>>>(kw, kmax2);
  k_attn12<<<(B_*H_)*(T_/64), 256, 0, stream>>>(qw, kw, vt, mw, kmax2, ao);
  k_proj_ln1<<<M_/64, 256, 0, stream>>>(ao, wot, bo, x, g1, be1, y32, yb);
  k_ff1   <<<M_/16, 256, 0, stream>>>(yb, w1t, bf1, hb);
  k_ff2_ln2<<<M_/64, 256, 0, stream>>>(hb, w2t, b2, y32, g2, be2, (float*)d_out);
}

// Round 13
// 209.932 us; speedup vs baseline: 1.0966x; 1.0966x over previous
//
#include <hip/hip_runtime.h>
#include <hip/hip_bf16.h>
#include <math.h>

// GNNLayer: B=4,T=4096,D=128,H=4,DH=32,FF=256
// bf16 MFMA (16x16x32) everywhere, fp32 accum, fp32 LN/residual/bias.
// R13: attn = exact R10 (92.7us proven; R12 barrier reverted). k_pack = R10
//      scalar (R12 uint4 version suspected regression). knorm = 256-block.
//      NEW: k_tail fuses proj+LN1 -> FF1+GELU -> FF2+LN2 per 16-row tile,
//      staging y (f32+bf16) and gelu(h) in LDS (rows padded: 136/264 u16 to
//      break stride-128 bank conflicts). Kills yb/hb/y32 HBM round-trips
//      (~40MB) and 2 launches. All MFMA/reduce patterns cloned from proven
//      kernels; LN sums cross-wave via LDS partials.

#define B_ 4
#define T_ 4096
#define D_ 128
#define H_ 4
#define DH_ 32
#define FF_ 256
#define M_ (B_*T_)

typedef unsigned short u16;
typedef __attribute__((ext_vector_type(8))) short bf16x8;
typedef __attribute__((ext_vector_type(4))) float f32x4;
typedef __attribute__((ext_vector_type(4))) u16 u16x4;

// ---- workspace layout (bytes, 256-aligned) ----
constexpr size_t OFF_FLAG  = 0;     // int flag @0, float kmax2[16] @64
constexpr size_t OFF_MASKW = 256;                      // u32[T][T/32] = 2 MB
constexpr size_t OFF_XB    = OFF_MASKW + 2097152;      // bf16 x        4 MB
constexpr size_t OFF_WQKVT = OFF_XB    + 4194304;      // bf16 [384][128]
constexpr size_t OFF_WOT   = OFF_WQKVT + 98304;        // bf16 [128][128]
constexpr size_t OFF_W1T   = OFF_WOT   + 32768;        // bf16 [256][128]
constexpr size_t OFF_W2T   = OFF_W1T   + 65536;        // bf16 [128][256]
constexpr size_t OFF_QW    = OFF_W2T   + 65536;        // bf16 [16][T][32] (q, pre-scaled 1/sqrt(DH))
constexpr size_t OFF_KW    = OFF_QW    + 4194304;      // bf16 [16][T*32] fragment-major
constexpr size_t OFF_VT    = OFF_KW    + 4194304;      // bf16 [16][T*32] fragment-major v^T
constexpr size_t OFF_AO    = OFF_VT    + 4194304;      // bf16 attn out [M][128]

__device__ __forceinline__ u16 f2bf(float f){
  unsigned u = __float_as_uint(f);
  u += 0x7FFFu + ((u >> 16) & 1u);
  return (u16)(u >> 16);
}

__device__ __forceinline__ float bf2f(u16 b){
  return __uint_as_float((unsigned)b << 16);
}

// frag loader (row-major source, works for global or LDS):
// p = base + row*stride + k0 + 4*(lane>>4)
__device__ __forceinline__ bf16x8 load_frag(const u16* p){
  union { bf16x8 v; uint2 u[2]; } f;
  f.u[0] = *(const uint2*)(p);
  f.u[1] = *(const uint2*)(p + 16);
  return f.v;
}

// ---- mask dtype detection + kmax2 zeroing ----
__global__ void k_detect(const unsigned* m, int* flag, float* kmax2){
  if (threadIdx.x < 16) kmax2[threadIdx.x] = 0.f;
  __shared__ int s_i32, s_f32;
  if (threadIdx.x == 0){ s_i32 = 1; s_f32 = 1; }
  __syncthreads();
  int li = 1, lf = 1;
  for (int i = threadIdx.x; i < 16384; i += 256){
    unsigned w = m[i];
    li &= (w <= 1u);
    lf &= (w == 0u || w == 0x3F800000u);
  }
  if (!li) atomicAnd(&s_i32, 0);
  if (!lf) atomicAnd(&s_f32, 0);
  __syncthreads();
  if (threadIdx.x == 0) *flag = (s_i32 | s_f32);
}

// pack (adj | eye) into bits: mw[i*128 + j/32] bit (j%32). (R10 version)
__global__ void k_pack(const void* mask, const int* flag, unsigned* mw){
  int idx = blockIdx.x*256 + threadIdx.x;   // word index, T*T/32 total
  int i = idx >> 7, wj = idx & 127;
  unsigned w = 0;
  if (*flag){
    const unsigned* p = (const unsigned*)mask + (size_t)i*T_ + wj*32;
    #pragma unroll
    for (int c = 0; c < 32; c++) w |= (p[c] != 0u ? 1u : 0u) << c;
  } else {
    const unsigned char* p = (const unsigned char*)mask + (size_t)i*T_ + wj*32;
    #pragma unroll
    for (int c = 0; c < 32; c++) w |= (p[c] ? 1u : 0u) << c;
  }
  if ((i >> 5) == wj) w |= 1u << (i & 31);
  mw[idx] = w;
}

__global__ void k_conv_x(const float* x, u16* xb){
  int i = (blockIdx.x*256 + threadIdx.x)*4;
  float4 v = *(const float4*)(x + i);
  u16x4 o = { f2bf(v.x), f2bf(v.y), f2bf(v.z), f2bf(v.w) };
  *(u16x4*)(xb + i) = o;
}

// weights -> bf16, transposed [N][K]
__global__ void k_conv_w(const float* Wq, const float* Wk, const float* Wv, const float* Wo,
                         const float* W1, const float* W2,
                         u16* wqkvt, u16* wot, u16* w1t, u16* w2t){
  int idx = blockIdx.x*256 + threadIdx.x;
  if (idx < 49152){                      // wqkvt[n<384][k<128]
    int n = idx >> 7, k = idx & 127;
    float v = (n < 128) ? Wq[k*128 + n] : (n < 256 ? Wk[k*128 + (n-128)] : Wv[k*128 + (n-256)]);
    wqkvt[idx] = f2bf(v);
  } else if (idx < 65536){               // wot[n<128][k<128]
    int j = idx - 49152, n = j >> 7, k = j & 127;
    wot[j] = f2bf(Wo[k*128 + n]);
  } else if (idx < 98304){               // w1t[n<256][k<128]
    int j = idx - 65536, n = j >> 7, k = j & 127;
    w1t[j] = f2bf(W1[k*256 + n]);
  } else if (idx < 131072){              // w2t[n<128][k<256]
    int j = idx - 98304, n = j >> 8, k = j & 255;
    w2t[j] = f2bf(W2[k*128 + n]);
  }
}

// QKV GEMM: grid 1024 (16 rows each), 4 waves x 96 cols. q scaled by 1/sqrt(32).
// K and V written in fragment-major layouts.
__global__ __launch_bounds__(256) void k_qkv(const u16* xb, const u16* wt,
    const float* bq, const float* bk, const float* bv,
    u16* qw, u16* kw, u16* vt){
  const int wv = threadIdx.x >> 6, lane = threadIdx.x & 63;
  const int r15 = lane & 15, g = lane >> 4;
  const int m0 = blockIdx.x * 16;
  f32x4 acc[6] = {};
  const u16* ar = xb + (size_t)(m0 + r15)*D_ + 4*g;
  #pragma unroll
  for (int kk = 0; kk < D_; kk += 32){
    bf16x8 af = load_frag(ar + kk);
    #pragma unroll
    for (int nf = 0; nf < 6; nf++){
      const u16* br = wt + (size_t)(wv*96 + nf*16 + r15)*D_ + kk + 4*g;
      acc[nf] = __builtin_amdgcn_mfma_f32_16x16x32_bf16(af, load_frag(br), acc[nf], 0, 0, 0);
    }
  }
  const int b = m0 >> 12, t0 = m0 & (T_-1);
  #pragma unroll
  for (int nf = 0; nf < 6; nf++){
    int ncol = wv*96 + nf*16 + r15;
    if (ncol < 128){
      int h = ncol >> 5, d = ncol & 31;
      float bias = bq[ncol];
      u16* dst = qw + ((size_t)(b*H_ + h)*T_)*DH_;
      #pragma unroll
      for (int rr = 0; rr < 4; rr++){
        int t = t0 + 4*g + rr;
        dst[(size_t)t*DH_ + d] = f2bf((acc[nf][rr] + bias) * 0.17677669529663687f);  // 1/sqrt(32)
      }
    } else if (ncol < 256){
      // K fragment-major: S_k(t,d) = (t>>4)*512 + ((d>>2)&3)*128 + (t&15)*8 + 4*(d>>4) + (d&3)
      int c = ncol - 128, h = c >> 5, d = c & 31;
      float bias = bk[c];
      u16* dst = kw + (size_t)(b*H_ + h)*T_*DH_
               + (size_t)(t0 >> 4)*512 + (size_t)((d >> 2) & 3)*128 + 4*(d >> 4) + (d & 3);
      #pragma unroll
      for (int rr = 0; rr < 4; rr++)
        dst[(4*g + rr)*8] = f2bf(acc[nf][rr] + bias);   // t&15 = 4g+rr
    } else {
      // V fragment-major: key t=t0+4g+rr, fixed d. base + rr are consecutive elems.
      int c = ncol - 256, h = c >> 5, d = c & 31;
      float bias = bv[c];
      int t = t0 + 4*g;
      int tin = t & 31;
      u16x4 v4;
      #pragma unroll
      for (int rr = 0; rr < 4; rr++) v4[rr] = f2bf(acc[nf][rr] + bias);
      u16* dst = vt + (size_t)(b*H_ + h)*T_*DH_
               + (size_t)(t >> 5)*1024 + (size_t)(d >> 4)*512
               + (size_t)(g*16 + (d & 15))*8 + 4*(tin >> 4);
      *(u16x4*)dst = v4;
    }
  }
}

// max_j ||k_j||^2 per (b,h) -> kmax2[bh]. Grid 256 (16 bh x 16 slices), 1 key/thread.
__global__ void k_knorm(const u16* kw, float* kmax2){
  const int bh = blockIdx.x >> 4, slice = blockIdx.x & 15;
  const int t = slice*256 + threadIdx.x;
  const u16* base = kw + (size_t)bh*T_*DH_ + (size_t)(t >> 4)*512 + (t & 15)*8;
  float s = 0.f;
  #pragma unroll
  for (int g = 0; g < 4; g++){
    union { uint4 u4; u16 e[8]; } v;
    v.u4 = *(const uint4*)(base + g*128);
    #pragma unroll
    for (int j = 0; j < 8; j++){ float f = bf2f(v.e[j]); s += f*f; }
  }
  float mx = s;
  #pragma unroll
  for (int d = 1; d < 64; d <<= 1) mx = fmaxf(mx, __shfl_xor(mx, d));
  if ((threadIdx.x & 63) == 0) atomicMax((unsigned*)(kmax2 + bh), __float_as_uint(mx));
}

// Bounded-softmax attention (__expf). Swapped QK^T; shift+mask in C-init;
// l via ones-column MFMA; pack via __float22bfloat162_rn. (exact R10 kernel)
// grid = BH(16) * T/64 = 1024; 4 waves/block, 16 queries/wave. XCD swizzle.
__global__ __launch_bounds__(256, 4) void k_attn13(const u16* qw, const u16* kw, const u16* vt,
    const unsigned* mw, const float* kmax2, u16* ao){
  const int wg = (blockIdx.x & 7)*128 + (blockIdx.x >> 3);   // 8 XCDs x 128 contiguous
  const int wv = threadIdx.x >> 6, lane = threadIdx.x & 63;
  const int r15 = lane & 15, g = lane >> 4;
  const int bh = wg >> 6;
  const int q0 = (wg & 63)*64 + wv*16;
  const u16* qp = qw + (size_t)bh*T_*DH_;
  const u16* kl = kw + (size_t)bh*T_*DH_ + lane*8;   // fragment-major, lane offset folded
  const u16* vl = vt + (size_t)bh*T_*DH_ + lane*8;
  const unsigned* mrow = mw + (size_t)(q0 + r15)*(T_/32);
  const bf16x8 qf = load_frag(qp + (size_t)(q0 + r15)*DH_ + 4*g);
  float n0 = 0.f;
  #pragma unroll
  for (int j = 0; j < 8; j++){ float f = bf2f((u16)qf[j]); n0 += f*f; }
  n0 += __shfl_xor(n0, 16); n0 += __shfl_xor(n0, 32);
  const float bnd = sqrtf(n0 * kmax2[bh]) * 1.0001f + 1e-6f;  // >= max_j |q.k_j|
  union { u16 e[8]; bf16x8 v; } ones;
  #pragma unroll
  for (int j = 0; j < 8; j++) ones.e[j] = 0x3F80;
  f32x4 o0 = {}, o1 = {}, ol = {};
  for (int jb4 = 0; jb4 < T_; jb4 += 128){
    const uint4 wv4 = *(const uint4*)(mrow + (jb4 >> 5));
    #pragma unroll
    for (int ji = 0; ji < 4; ji++){
      const int jb = jb4 + ji*32;
      const unsigned w = ((const unsigned*)&wv4)[ji];
      const unsigned u = w >> (4*g);
      bf16x8 kf0 = *(const bf16x8*)(kl + (size_t)(jb >> 4)*512);
      bf16x8 kf1 = *(const bf16x8*)(kl + (size_t)((jb >> 4) + 1)*512);
      bf16x8 vf0 = *(const bf16x8*)(vl + (size_t)(jb >> 5)*1024);
      bf16x8 vf1 = *(const bf16x8*)(vl + (size_t)(jb >> 5)*1024 + 512);
      f32x4 c0, c1;   // -bnd if masked-in else -1e30 (exp -> 0)
      #pragma unroll
      for (int rr = 0; rr < 4; rr++){
        c0[rr] = ((u >> rr) & 1u)        ? -bnd : -1e30f;
        c1[rr] = ((u >> (16 + rr)) & 1u) ? -bnd : -1e30f;
      }
      f32x4 s0 = __builtin_amdgcn_mfma_f32_16x16x32_bf16(kf0, qf, c0, 0, 0, 0);
      f32x4 s1 = __builtin_amdgcn_mfma_f32_16x16x32_bf16(kf1, qf, c1, 0, 0, 0);
      float p0[4], p1[4];
      #pragma unroll
      for (int rr = 0; rr < 4; rr++){
        p0[rr] = __expf(s0[rr]);
        p1[rr] = __expf(s1[rr]);
      }
      union { bf16x8 v; __hip_bfloat162 h2[4]; } pf;
      pf.h2[0] = __float22bfloat162_rn(make_float2(p0[0], p0[1]));
      pf.h2[1] = __float22bfloat162_rn(make_float2(p0[2], p0[3]));
      pf.h2[2] = __float22bfloat162_rn(make_float2(p1[0], p1[1]));
      pf.h2[3] = __float22bfloat162_rn(make_float2(p1[2], p1[3]));
      o0 = __builtin_amdgcn_mfma_f32_16x16x32_bf16(pf.v, vf0, o0, 0, 0, 0);
      o1 = __builtin_amdgcn_mfma_f32_16x16x32_bf16(pf.v, vf1, o1, 0, 0, 0);
      ol = __builtin_amdgcn_mfma_f32_16x16x32_bf16(pf.v, ones.v, ol, 0, 0, 0);
    }
  }
  const int b = bh >> 2, h = bh & 3;
  #pragma unroll
  for (int rr = 0; rr < 4; rr++){
    float li = ol[rr];                  // l for query 4g+rr, present in every lane
    float inv = li > 0.f ? 1.f/li : 0.f;
    size_t row = (size_t)(b*T_ + q0 + 4*g + rr)*D_;
    ao[row + h*DH_ + r15]      = f2bf(o0[rr]*inv);
    ao[row + h*DH_ + 16 + r15] = f2bf(o1[rr]*inv);
  }
}

// Fused tail: proj+residual+LN1 -> FF1+GELU -> FF2+residual+LN2 -> out.
// grid 1024 (16 rows/block), 4 waves. y/h staged in LDS (padded rows).
__global__ __launch_bounds__(256) void k_tail(const u16* ao, const u16* wot, const float* bo,
    const float* x, const float* g1, const float* be1,
    const u16* w1t, const float* bf1, const u16* w2t, const float* b2,
    const float* g2, const float* be2, float* out){
  __shared__ float ly[16][132];     // y32 (LN1 out, f32) - LN2 residual
  __shared__ u16  lyb[16][136];     // y bf16 (A for FF1); pad 136 breaks bank conflict
  __shared__ u16  lhb[16][264];     // gelu(h) bf16 (A for FF2); pad 264
  __shared__ float rs[4][16], rq[4][16];
  const int wv = threadIdx.x >> 6, lane = threadIdx.x & 63;
  const int r15 = lane & 15, g = lane >> 4;
  const int m0 = blockIdx.x * 16;

  // ---- stage A: proj GEMM (wave wv -> cols [wv*32, wv*32+32)) ----
  f32x4 accA[2] = {};
  const u16* ar = ao + (size_t)(m0 + r15)*D_ + 4*g;
  #pragma unroll
  for (int kk = 0; kk < D_; kk += 32){
    bf16x8 af = load_frag(ar + kk);
    #pragma unroll
    for (int nf = 0; nf < 2; nf++)
      accA[nf] = __builtin_amdgcn_mfma_f32_16x16x32_bf16(af,
          load_frag(wot + (size_t)((wv*2 + nf)*16 + r15)*D_ + kk + 4*g), accA[nf], 0, 0, 0);
  }
  float tA[2][4];
  #pragma unroll
  for (int rr = 0; rr < 4; rr++){
    float s1 = 0.f, s2 = 0.f;
    #pragma unroll
    for (int nf = 0; nf < 2; nf++){
      int col = (wv*2 + nf)*16 + r15;
      float t = accA[nf][rr] + bo[col] + x[(size_t)(m0 + 4*g + rr)*D_ + col];
      tA[nf][rr] = t; s1 += t; s2 += t*t;
    }
    #pragma unroll
    for (int d = 1; d < 16; d <<= 1){ s1 += __shfl_xor(s1, d); s2 += __shfl_xor(s2, d); }
    if (r15 == 0){ rs[wv][4*g + rr] = s1; rq[wv][4*g + rr] = s2; }
  }
  __syncthreads();
  #pragma unroll
  for (int rr = 0; rr < 4; rr++){
    int row = 4*g + rr;
    float S1 = rs[0][row] + rs[1][row] + rs[2][row] + rs[3][row];
    float S2 = rq[0][row] + rq[1][row] + rq[2][row] + rq[3][row];
    float mu = S1 * (1.f/D_);
    float var = fmaxf(S2 * (1.f/D_) - mu*mu, 0.f);
    float inv = rsqrtf(var + 1e-5f);
    #pragma unroll
    for (int nf = 0; nf < 2; nf++){
      int col = (wv*2 + nf)*16 + r15;
      float o = (tA[nf][rr] - mu)*inv*g1[col] + be1[col];
      ly[row][col] = o;
      lyb[row][col] = f2bf(o);
    }
  }
  __syncthreads();

  // ---- stage B: FF1 + GELU (wave wv -> cols [wv*64, wv*64+64)) ----
  const int n0w = wv*64;
  f32x4 accB[4] = {};
  #pragma unroll
  for (int kk = 0; kk < D_; kk += 32){
    bf16x8 af = load_frag(&lyb[r15][kk + 4*g]);
    #pragma unroll
    for (int nf = 0; nf < 4; nf++)
      accB[nf] = __builtin_amdgcn_mfma_f32_16x16x32_bf16(af,
          load_frag(w1t + (size_t)(n0w + nf*16 + r15)*D_ + kk + 4*g), accB[nf], 0, 0, 0);
  }
  #pragma unroll
  for (int nf = 0; nf < 4; nf++){
    int col = n0w + nf*16 + r15;
    float bias = bf1[col];
    #pragma unroll
    for (int rr = 0; rr < 4; rr++){
      float vv = accB[nf][rr] + bias;
      // gelu(x) = x*t/(t+1), t=exp(2z), z=sqrt(2/pi)(x+0.044715x^3); max dev 3e-4
      float z2 = fminf(1.5957691216057308f*vv + 0.07135581778225507f*vv*vv*vv, 80.f);
      float t = __expf(z2);
      lhb[4*g + rr][col] = f2bf(vv * t / (t + 1.f));
    }
  }
  __syncthreads();

  // ---- stage C: FF2 + residual + LN2 (wave wv -> cols [wv*32, wv*32+32)) ----
  f32x4 accC[2] = {};
  #pragma unroll
  for (int kk = 0; kk < FF_; kk += 32){
    bf16x8 af = load_frag(&lhb[r15][kk + 4*g]);
    #pragma unroll
    for (int nf = 0; nf < 2; nf++)
      accC[nf] = __builtin_amdgcn_mfma_f32_16x16x32_bf16(af,
          load_frag(w2t + (size_t)((wv*2 + nf)*16 + r15)*FF_ + kk + 4*g), accC[nf], 0, 0, 0);
  }
  float tC[2][4];
  #pragma unroll
  for (int rr = 0; rr < 4; rr++){
    float s1 = 0.f, s2 = 0.f;
    #pragma unroll
    for (int nf = 0; nf < 2; nf++){
      int col = (wv*2 + nf)*16 + r15;
      float t = accC[nf][rr] + b2[col] + ly[4*g + rr][col];
      tC[nf][rr] = t; s1 += t; s2 += t*t;
    }
    #pragma unroll
    for (int d = 1; d < 16; d <<= 1){ s1 += __shfl_xor(s1, d); s2 += __shfl_xor(s2, d); }
    if (r15 == 0){ rs[wv][4*g + rr] = s1; rq[wv][4*g + rr] = s2; }
  }
  __syncthreads();
  #pragma unroll
  for (int rr = 0; rr < 4; rr++){
    int row = 4*g + rr;
    float S1 = rs[0][row] + rs[1][row] + rs[2][row] + rs[3][row];
    float S2 = rq[0][row] + rq[1][row] + rq[2][row] + rq[3][row];
    float mu = S1 * (1.f/D_);
    float var = fmaxf(S2 * (1.f/D_) - mu*mu, 0.f);
    float inv = rsqrtf(var + 1e-5f);
    #pragma unroll
    for (int nf = 0; nf < 2; nf++){
      int col = (wv*2 + nf)*16 + r15;
      out[(size_t)(m0 + row)*D_ + col] = (tC[nf][rr] - mu)*inv*g2[col] + be2[col];
    }
  }
}

extern "C" void kernel_launch(void* const* d_in, const int* in_sizes, int n_in,
                              void* d_out, int out_size, void* d_ws, size_t ws_size,
                              hipStream_t stream){
  const float* x   = (const float*)d_in[0];
  const void*  msk = d_in[1];
  const float* Wq = (const float*)d_in[2];  const float* bq  = (const float*)d_in[3];
  const float* Wk = (const float*)d_in[4];  const float* bk  = (const float*)d_in[5];
  const float* Wv = (const float*)d_in[6];  const float* bv  = (const float*)d_in[7];
  const float* Wo = (const float*)d_in[8];  const float* bo  = (const float*)d_in[9];
  const float* g1 = (const float*)d_in[10]; const float* be1 = (const float*)d_in[11];
  const float* W1 = (const float*)d_in[12]; const float* bf1 = (const float*)d_in[13];
  const float* W2 = (const float*)d_in[14]; const float* b2  = (const float*)d_in[15];
  const float* g2 = (const float*)d_in[16]; const float* be2 = (const float*)d_in[17];

  char* ws = (char*)d_ws;
  int*      flag  = (int*)     (ws + OFF_FLAG);
  float*    kmax2 = (float*)   (ws + OFF_FLAG + 64);
  unsigned* mw    = (unsigned*)(ws + OFF_MASKW);
  u16* xb    = (u16*)(ws + OFF_XB);
  u16* wqkvt = (u16*)(ws + OFF_WQKVT);
  u16* wot   = (u16*)(ws + OFF_WOT);
  u16* w1t   = (u16*)(ws + OFF_W1T);
  u16* w2t   = (u16*)(ws + OFF_W2T);
  u16* qw    = (u16*)(ws + OFF_QW);
  u16* kw    = (u16*)(ws + OFF_KW);
  u16* vt    = (u16*)(ws + OFF_VT);
  u16* ao    = (u16*)(ws + OFF_AO);

  k_detect<<<1, 256, 0, stream>>>((const unsigned*)msk, flag, kmax2);
  k_pack  <<<(T_*T_/32)/256, 256, 0, stream>>>(msk, flag, mw);
  k_conv_x<<<(M_*D_/4)/256, 256, 0, stream>>>(x, xb);
  k_conv_w<<<131072/256, 256, 0, stream>>>(Wq, Wk, Wv, Wo, W1, W2, wqkvt, wot, w1t, w2t);
  k_qkv   <<<M_/16, 256, 0, stream>>>(xb, wqkvt, bq, bk, bv, qw, kw, vt);
  k_knorm <<<(B_*H_)*16, 256, 0, stream>>>(kw, kmax2);
  k_attn13<<<(B_*H_)*(T_/64), 256, 0, stream>>>(qw, kw, vt, mw, kmax2, ao);
  k_tail  <<<M_/16, 256, 0, stream>>>(ao, wot, bo, x, g1, be1, w1t, bf1, w2t, b2, g2, be2, (float*)d_out);
}

// Round 14
// 209.379 us; speedup vs baseline: 1.0995x; 1.0026x over previous
//
#include <hip/hip_runtime.h>
#include <hip/hip_bf16.h>
#include <math.h>

// GNNLayer: B=4,T=4096,D=128,H=4,DH=32,FF=256
// bf16 MFMA (16x16x32) everywhere, fp32 accum, fp32 LN/residual/bias.
// R14: R13 + k_qkv epilogue rework. Old epilogue: 24 scalar 2B global stores
//      per thread (K fragment-major = 16 segments/instr). New: stage the
//      16x384 tile in LDS ([16][392] u16, padded), barrier, emit vectorized:
//      Q 256x16B row-major, K 256x16B (fragment-major contiguous per
//      (seg,trow)), V 512x8B. Same layout formulas as R5-proven producer.

#define B_ 4
#define T_ 4096
#define D_ 128
#define H_ 4
#define DH_ 32
#define FF_ 256
#define M_ (B_*T_)

typedef unsigned short u16;
typedef __attribute__((ext_vector_type(8))) short bf16x8;
typedef __attribute__((ext_vector_type(4))) float f32x4;
typedef __attribute__((ext_vector_type(4))) u16 u16x4;

// ---- workspace layout (bytes, 256-aligned) ----
constexpr size_t OFF_FLAG  = 0;     // int flag @0, float kmax2[16] @64
constexpr size_t OFF_MASKW = 256;                      // u32[T][T/32] = 2 MB
constexpr size_t OFF_XB    = OFF_MASKW + 2097152;      // bf16 x        4 MB
constexpr size_t OFF_WQKVT = OFF_XB    + 4194304;      // bf16 [384][128]
constexpr size_t OFF_WOT   = OFF_WQKVT + 98304;        // bf16 [128][128]
constexpr size_t OFF_W1T   = OFF_WOT   + 32768;        // bf16 [256][128]
constexpr size_t OFF_W2T   = OFF_W1T   + 65536;        // bf16 [128][256]
constexpr size_t OFF_QW    = OFF_W2T   + 65536;        // bf16 [16][T][32] (q, pre-scaled 1/sqrt(DH))
constexpr size_t OFF_KW    = OFF_QW    + 4194304;      // bf16 [16][T*32] fragment-major
constexpr size_t OFF_VT    = OFF_KW    + 4194304;      // bf16 [16][T*32] fragment-major v^T
constexpr size_t OFF_AO    = OFF_VT    + 4194304;      // bf16 attn out [M][128]

__device__ __forceinline__ u16 f2bf(float f){
  unsigned u = __float_as_uint(f);
  u += 0x7FFFu + ((u >> 16) & 1u);
  return (u16)(u >> 16);
}

__device__ __forceinline__ float bf2f(u16 b){
  return __uint_as_float((unsigned)b << 16);
}

// frag loader (row-major source, works for global or LDS):
// p = base + row*stride + k0 + 4*(lane>>4)
__device__ __forceinline__ bf16x8 load_frag(const u16* p){
  union { bf16x8 v; uint2 u[2]; } f;
  f.u[0] = *(const uint2*)(p);
  f.u[1] = *(const uint2*)(p + 16);
  return f.v;
}

// ---- mask dtype detection + kmax2 zeroing ----
__global__ void k_detect(const unsigned* m, int* flag, float* kmax2){
  if (threadIdx.x < 16) kmax2[threadIdx.x] = 0.f;
  __shared__ int s_i32, s_f32;
  if (threadIdx.x == 0){ s_i32 = 1; s_f32 = 1; }
  __syncthreads();
  int li = 1, lf = 1;
  for (int i = threadIdx.x; i < 16384; i += 256){
    unsigned w = m[i];
    li &= (w <= 1u);
    lf &= (w == 0u || w == 0x3F800000u);
  }
  if (!li) atomicAnd(&s_i32, 0);
  if (!lf) atomicAnd(&s_f32, 0);
  __syncthreads();
  if (threadIdx.x == 0) *flag = (s_i32 | s_f32);
}

// pack (adj | eye) into bits: mw[i*128 + j/32] bit (j%32).
__global__ void k_pack(const void* mask, const int* flag, unsigned* mw){
  int idx = blockIdx.x*256 + threadIdx.x;   // word index, T*T/32 total
  int i = idx >> 7, wj = idx & 127;
  unsigned w = 0;
  if (*flag){
    const unsigned* p = (const unsigned*)mask + (size_t)i*T_ + wj*32;
    #pragma unroll
    for (int c = 0; c < 32; c++) w |= (p[c] != 0u ? 1u : 0u) << c;
  } else {
    const unsigned char* p = (const unsigned char*)mask + (size_t)i*T_ + wj*32;
    #pragma unroll
    for (int c = 0; c < 32; c++) w |= (p[c] ? 1u : 0u) << c;
  }
  if ((i >> 5) == wj) w |= 1u << (i & 31);
  mw[idx] = w;
}

__global__ void k_conv_x(const float* x, u16* xb){
  int i = (blockIdx.x*256 + threadIdx.x)*4;
  float4 v = *(const float4*)(x + i);
  u16x4 o = { f2bf(v.x), f2bf(v.y), f2bf(v.z), f2bf(v.w) };
  *(u16x4*)(xb + i) = o;
}

// weights -> bf16, transposed [N][K]
__global__ void k_conv_w(const float* Wq, const float* Wk, const float* Wv, const float* Wo,
                         const float* W1, const float* W2,
                         u16* wqkvt, u16* wot, u16* w1t, u16* w2t){
  int idx = blockIdx.x*256 + threadIdx.x;
  if (idx < 49152){                      // wqkvt[n<384][k<128]
    int n = idx >> 7, k = idx & 127;
    float v = (n < 128) ? Wq[k*128 + n] : (n < 256 ? Wk[k*128 + (n-128)] : Wv[k*128 + (n-256)]);
    wqkvt[idx] = f2bf(v);
  } else if (idx < 65536){               // wot[n<128][k<128]
    int j = idx - 49152, n = j >> 7, k = j & 127;
    wot[j] = f2bf(Wo[k*128 + n]);
  } else if (idx < 98304){               // w1t[n<256][k<128]
    int j = idx - 65536, n = j >> 7, k = j & 127;
    w1t[j] = f2bf(W1[k*256 + n]);
  } else if (idx < 131072){              // w2t[n<128][k<256]
    int j = idx - 98304, n = j >> 8, k = j & 255;
    w2t[j] = f2bf(W2[k*128 + n]);
  }
}

// QKV GEMM: grid 1024 (16 rows each), 4 waves x 96 cols. q scaled by 1/sqrt(32).
// Epilogue: LDS-staged, vectorized coalesced stores into fragment-major K/V.
__global__ __launch_bounds__(256) void k_qkv(const u16* xb, const u16* wt,
    const float* bq, const float* bk, const float* bv,
    u16* qw, u16* kw, u16* vt){
  __shared__ u16 st[16][392];   // [row in tile][ncol 0..383], pad 392
  const int wv = threadIdx.x >> 6, lane = threadIdx.x & 63;
  const int r15 = lane & 15, g = lane >> 4;
  const int m0 = blockIdx.x * 16;
  f32x4 acc[6] = {};
  const u16* ar = xb + (size_t)(m0 + r15)*D_ + 4*g;
  #pragma unroll
  for (int kk = 0; kk < D_; kk += 32){
    bf16x8 af = load_frag(ar + kk);
    #pragma unroll
    for (int nf = 0; nf < 6; nf++){
      const u16* br = wt + (size_t)(wv*96 + nf*16 + r15)*D_ + kk + 4*g;
      acc[nf] = __builtin_amdgcn_mfma_f32_16x16x32_bf16(af, load_frag(br), acc[nf], 0, 0, 0);
    }
  }
  // stage to LDS with bias (+ q scale)
  #pragma unroll
  for (int nf = 0; nf < 6; nf++){
    int ncol = wv*96 + nf*16 + r15;
    float bias = (ncol < 128) ? bq[ncol] : (ncol < 256 ? bk[ncol-128] : bv[ncol-256]);
    float scl  = (ncol < 128) ? 0.17677669529663687f : 1.f;   // 1/sqrt(32) on q
    #pragma unroll
    for (int rr = 0; rr < 4; rr++)
      st[4*g + rr][ncol] = f2bf((acc[nf][rr] + bias) * scl);
  }
  __syncthreads();
  // vectorized emit
  const int b = m0 >> 12, t0m = m0 & (T_-1);
  const int i = threadIdx.x;
  // Q: 256 x 16B. i -> t=i>>4, c=i&15 (h=c>>2, d0=(c&3)*8)
  {
    const int t = i >> 4, c = i & 15, h = c >> 2, d0 = (c & 3)*8;
    uint4 v = *(const uint4*)&st[t][h*32 + d0];
    *(uint4*)(qw + ((size_t)(b*H_ + h)*T_ + (t0m + t))*DH_ + d0) = v;
  }
  // K: 256 x 16B. i -> h=i>>6, seg=(i>>4)&3, trow=i&15.
  // elem(sub 0..7): d = 16*(sub>>2) + 4*seg + (sub&3); src col 128 + h*32 + d
  {
    const int h = i >> 6, seg = (i >> 4) & 3, trow = i & 15;
    union { u16 e[8]; uint4 u; } v;
    #pragma unroll
    for (int sub = 0; sub < 8; sub++){
      int d = 16*(sub >> 2) + 4*seg + (sub & 3);
      v.e[sub] = st[trow][128 + h*32 + d];
    }
    *(uint4*)(kw + (size_t)(b*H_ + h)*T_*DH_ + (size_t)(t0m >> 4)*512 + seg*128 + trow*8) = v.u;
  }
  // V: 512 x 8B (2 chunks/thread). chunk c -> h=c>>7, dlhi=(c>>6)&1, tq=(c>>4)&3, dl15=c&15.
  // rows t = tq*4 + j (j 0..3); dst offset = (t0m>>5)*1024 + dlhi*512 +
  //   (tq*16 + dl15)*8 + 4*((t0m>>4)&1)
  {
    const int bit4 = (t0m >> 4) & 1;
    #pragma unroll
    for (int cc = 0; cc < 2; cc++){
      const int c = i + cc*256;
      const int h = c >> 7, dlhi = (c >> 6) & 1, tq = (c >> 4) & 3, dl15 = c & 15;
      u16x4 v;
      #pragma unroll
      for (int j = 0; j < 4; j++)
        v[j] = st[tq*4 + j][256 + h*32 + dlhi*16 + dl15];
      *(u16x4*)(vt + (size_t)(b*H_ + h)*T_*DH_ + (size_t)(t0m >> 5)*1024
                + dlhi*512 + (size_t)(tq*16 + dl15)*8 + 4*bit4) = v;
    }
  }
}

// max_j ||k_j||^2 per (b,h) -> kmax2[bh]. Grid 256 (16 bh x 16 slices), 1 key/thread.
__global__ void k_knorm(const u16* kw, float* kmax2){
  const int bh = blockIdx.x >> 4, slice = blockIdx.x & 15;
  const int t = slice*256 + threadIdx.x;
  const u16* base = kw + (size_t)bh*T_*DH_ + (size_t)(t >> 4)*512 + (t & 15)*8;
  float s = 0.f;
  #pragma unroll
  for (int g = 0; g < 4; g++){
    union { uint4 u4; u16 e[8]; } v;
    v.u4 = *(const uint4*)(base + g*128);
    #pragma unroll
    for (int j = 0; j < 8; j++){ float f = bf2f(v.e[j]); s += f*f; }
  }
  float mx = s;
  #pragma unroll
  for (int d = 1; d < 64; d <<= 1) mx = fmaxf(mx, __shfl_xor(mx, d));
  if ((threadIdx.x & 63) == 0) atomicMax((unsigned*)(kmax2 + bh), __float_as_uint(mx));
}

// Bounded-softmax attention (__expf). Swapped QK^T; shift+mask in C-init;
// l via ones-column MFMA; pack via __float22bfloat162_rn. (exact R10 kernel)
// grid = BH(16) * T/64 = 1024; 4 waves/block, 16 queries/wave. XCD swizzle.
__global__ __launch_bounds__(256, 4) void k_attn14(const u16* qw, const u16* kw, const u16* vt,
    const unsigned* mw, const float* kmax2, u16* ao){
  const int wg = (blockIdx.x & 7)*128 + (blockIdx.x >> 3);   // 8 XCDs x 128 contiguous
  const int wv = threadIdx.x >> 6, lane = threadIdx.x & 63;
  const int r15 = lane & 15, g = lane >> 4;
  const int bh = wg >> 6;
  const int q0 = (wg & 63)*64 + wv*16;
  const u16* qp = qw + (size_t)bh*T_*DH_;
  const u16* kl = kw + (size_t)bh*T_*DH_ + lane*8;   // fragment-major, lane offset folded
  const u16* vl = vt + (size_t)bh*T_*DH_ + lane*8;
  const unsigned* mrow = mw + (size_t)(q0 + r15)*(T_/32);
  const bf16x8 qf = load_frag(qp + (size_t)(q0 + r15)*DH_ + 4*g);
  float n0 = 0.f;
  #pragma unroll
  for (int j = 0; j < 8; j++){ float f = bf2f((u16)qf[j]); n0 += f*f; }
  n0 += __shfl_xor(n0, 16); n0 += __shfl_xor(n0, 32);
  const float bnd = sqrtf(n0 * kmax2[bh]) * 1.0001f + 1e-6f;  // >= max_j |q.k_j|
  union { u16 e[8]; bf16x8 v; } ones;
  #pragma unroll
  for (int j = 0; j < 8; j++) ones.e[j] = 0x3F80;
  f32x4 o0 = {}, o1 = {}, ol = {};
  for (int jb4 = 0; jb4 < T_; jb4 += 128){
    const uint4 wv4 = *(const uint4*)(mrow + (jb4 >> 5));
    #pragma unroll
    for (int ji = 0; ji < 4; ji++){
      const int jb = jb4 + ji*32;
      const unsigned w = ((const unsigned*)&wv4)[ji];
      const unsigned u = w >> (4*g);
      bf16x8 kf0 = *(const bf16x8*)(kl + (size_t)(jb >> 4)*512);
      bf16x8 kf1 = *(const bf16x8*)(kl + (size_t)((jb >> 4) + 1)*512);
      bf16x8 vf0 = *(const bf16x8*)(vl + (size_t)(jb >> 5)*1024);
      bf16x8 vf1 = *(const bf16x8*)(vl + (size_t)(jb >> 5)*1024 + 512);
      f32x4 c0, c1;   // -bnd if masked-in else -1e30 (exp -> 0)
      #pragma unroll
      for (int rr = 0; rr < 4; rr++){
        c0[rr] = ((u >> rr) & 1u)        ? -bnd : -1e30f;
        c1[rr] = ((u >> (16 + rr)) & 1u) ? -bnd : -1e30f;
      }
      f32x4 s0 = __builtin_amdgcn_mfma_f32_16x16x32_bf16(kf0, qf, c0, 0, 0, 0);
      f32x4 s1 = __builtin_amdgcn_mfma_f32_16x16x32_bf16(kf1, qf, c1, 0, 0, 0);
      float p0[4], p1[4];
      #pragma unroll
      for (int rr = 0; rr < 4; rr++){
        p0[rr] = __expf(s0[rr]);
        p1[rr] = __expf(s1[rr]);
      }
      union { bf16x8 v; __hip_bfloat162 h2[4]; } pf;
      pf.h2[0] = __float22bfloat162_rn(make_float2(p0[0], p0[1]));
      pf.h2[1] = __float22bfloat162_rn(make_float2(p0[2], p0[3]));
      pf.h2[2] = __float22bfloat162_rn(make_float2(p1[0], p1[1]));
      pf.h2[3] = __float22bfloat162_rn(make_float2(p1[2], p1[3]));
      o0 = __builtin_amdgcn_mfma_f32_16x16x32_bf16(pf.v, vf0, o0, 0, 0, 0);
      o1 = __builtin_amdgcn_mfma_f32_16x16x32_bf16(pf.v, vf1, o1, 0, 0, 0);
      ol = __builtin_amdgcn_mfma_f32_16x16x32_bf16(pf.v, ones.v, ol, 0, 0, 0);
    }
  }
  const int b = bh >> 2, h = bh & 3;
  #pragma unroll
  for (int rr = 0; rr < 4; rr++){
    float li = ol[rr];                  // l for query 4g+rr, present in every lane
    float inv = li > 0.f ? 1.f/li : 0.f;
    size_t row = (size_t)(b*T_ + q0 + 4*g + rr)*D_;
    ao[row + h*DH_ + r15]      = f2bf(o0[rr]*inv);
    ao[row + h*DH_ + 16 + r15] = f2bf(o1[rr]*inv);
  }
}

// Fused tail: proj+residual+LN1 -> FF1+GELU -> FF2+residual+LN2 -> out.
// grid 1024 (16 rows/block), 4 waves. y/h staged in LDS (padded rows).
__global__ __launch_bounds__(256) void k_tail(const u16* ao, const u16* wot, const float* bo,
    const float* x, const float* g1, const float* be1,
    const u16* w1t, const float* bf1, const u16* w2t, const float* b2,
    const float* g2, const float* be2, float* out){
  __shared__ float ly[16][132];     // y32 (LN1 out, f32) - LN2 residual
  __shared__ u16  lyb[16][136];     // y bf16 (A for FF1); pad 136 breaks bank conflict
  __shared__ u16  lhb[16][264];     // gelu(h) bf16 (A for FF2); pad 264
  __shared__ float rs[4][16], rq[4][16];
  const int wv = threadIdx.x >> 6, lane = threadIdx.x & 63;
  const int r15 = lane & 15, g = lane >> 4;
  const int m0 = blockIdx.x * 16;

  // ---- stage A: proj GEMM (wave wv -> cols [wv*32, wv*32+32)) ----
  f32x4 accA[2] = {};
  const u16* ar = ao + (size_t)(m0 + r15)*D_ + 4*g;
  #pragma unroll
  for (int kk = 0; kk < D_; kk += 32){
    bf16x8 af = load_frag(ar + kk);
    #pragma unroll
    for (int nf = 0; nf < 2; nf++)
      accA[nf] = __builtin_amdgcn_mfma_f32_16x16x32_bf16(af,
          load_frag(wot + (size_t)((wv*2 + nf)*16 + r15)*D_ + kk + 4*g), accA[nf], 0, 0, 0);
  }
  float tA[2][4];
  #pragma unroll
  for (int rr = 0; rr < 4; rr++){
    float s1 = 0.f, s2 = 0.f;
    #pragma unroll
    for (int nf = 0; nf < 2; nf++){
      int col = (wv*2 + nf)*16 + r15;
      float t = accA[nf][rr] + bo[col] + x[(size_t)(m0 + 4*g + rr)*D_ + col];
      tA[nf][rr] = t; s1 += t; s2 += t*t;
    }
    #pragma unroll
    for (int d = 1; d < 16; d <<= 1){ s1 += __shfl_xor(s1, d); s2 += __shfl_xor(s2, d); }
    if (r15 == 0){ rs[wv][4*g + rr] = s1; rq[wv][4*g + rr] = s2; }
  }
  __syncthreads();
  #pragma unroll
  for (int rr = 0; rr < 4; rr++){
    int row = 4*g + rr;
    float S1 = rs[0][row] + rs[1][row] + rs[2][row] + rs[3][row];
    float S2 = rq[0][row] + rq[1][row] + rq[2][row] + rq[3][row];
    float mu = S1 * (1.f/D_);
    float var = fmaxf(S2 * (1.f/D_) - mu*mu, 0.f);
    float inv = rsqrtf(var + 1e-5f);
    #pragma unroll
    for (int nf = 0; nf < 2; nf++){
      int col = (wv*2 + nf)*16 + r15;
      float o = (tA[nf][rr] - mu)*inv*g1[col] + be1[col];
      ly[row][col] = o;
      lyb[row][col] = f2bf(o);
    }
  }
  __syncthreads();

  // ---- stage B: FF1 + GELU (wave wv -> cols [wv*64, wv*64+64)) ----
  const int n0w = wv*64;
  f32x4 accB[4] = {};
  #pragma unroll
  for (int kk = 0; kk < D_; kk += 32){
    bf16x8 af = load_frag(&lyb[r15][kk + 4*g]);
    #pragma unroll
    for (int nf = 0; nf < 4; nf++)
      accB[nf] = __builtin_amdgcn_mfma_f32_16x16x32_bf16(af,
          load_frag(w1t + (size_t)(n0w + nf*16 + r15)*D_ + kk + 4*g), accB[nf], 0, 0, 0);
  }
  #pragma unroll
  for (int nf = 0; nf < 4; nf++){
    int col = n0w + nf*16 + r15;
    float bias = bf1[col];
    #pragma unroll
    for (int rr = 0; rr < 4; rr++){
      float vv = accB[nf][rr] + bias;
      // gelu(x) = x*t/(t+1), t=exp(2z), z=sqrt(2/pi)(x+0.044715x^3); max dev 3e-4
      float z2 = fminf(1.5957691216057308f*vv + 0.07135581778225507f*vv*vv*vv, 80.f);
      float t = __expf(z2);
      lhb[4*g + rr][col] = f2bf(vv * t / (t + 1.f));
    }
  }
  __syncthreads();

  // ---- stage C: FF2 + residual + LN2 (wave wv -> cols [wv*32, wv*32+32)) ----
  f32x4 accC[2] = {};
  #pragma unroll
  for (int kk = 0; kk < FF_; kk += 32){
    bf16x8 af = load_frag(&lhb[r15][kk + 4*g]);
    #pragma unroll
    for (int nf = 0; nf < 2; nf++)
      accC[nf] = __builtin_amdgcn_mfma_f32_16x16x32_bf16(af,
          load_frag(w2t + (size_t)((wv*2 + nf)*16 + r15)*FF_ + kk + 4*g), accC[nf], 0, 0, 0);
  }
  float tC[2][4];
  #pragma unroll
  for (int rr = 0; rr < 4; rr++){
    float s1 = 0.f, s2 = 0.f;
    #pragma unroll
    for (int nf = 0; nf < 2; nf++){
      int col = (wv*2 + nf)*16 + r15;
      float t = accC[nf][rr] + b2[col] + ly[4*g + rr][col];
      tC[nf][rr] = t; s1 += t; s2 += t*t;
    }
    #pragma unroll
    for (int d = 1; d < 16; d <<= 1){ s1 += __shfl_xor(s1, d); s2 += __shfl_xor(s2, d); }
    if (r15 == 0){ rs[wv][4*g + rr] = s1; rq[wv][4*g + rr] = s2; }
  }
  __syncthreads();
  #pragma unroll
  for (int rr = 0; rr < 4; rr++){
    int row = 4*g + rr;
    float S1 = rs[0][row] + rs[1][row] + rs[2][row] + rs[3][row];
    float S2 = rq[0][row] + rq[1][row] + rq[2][row] + rq[3][row];
    float mu = S1 * (1.f/D_);
    float var = fmaxf(S2 * (1.f/D_) - mu*mu, 0.f);
    float inv = rsqrtf(var + 1e-5f);
    #pragma unroll
    for (int nf = 0; nf < 2; nf++){
      int col = (wv*2 + nf)*16 + r15;
      out[(size_t)(m0 + row)*D_ + col] = (tC[nf][rr] - mu)*inv*g2[col] + be2[col];
    }
  }
}

extern "C" void kernel_launch(void* const* d_in, const int* in_sizes, int n_in,
                              void* d_out, int out_size, void* d_ws, size_t ws_size,
                              hipStream_t stream){
  const float* x   = (const float*)d_in[0];
  const void*  msk = d_in[1];
  const float* Wq = (const float*)d_in[2];  const float* bq  = (const float*)d_in[3];
  const float* Wk = (const float*)d_in[4];  const float* bk  = (const float*)d_in[5];
  const float* Wv = (const float*)d_in[6];  const float* bv  = (const float*)d_in[7];
  const float* Wo = (const float*)d_in[8];  const float* bo  = (const float*)d_in[9];
  const float* g1 = (const float*)d_in[10]; const float* be1 = (const float*)d_in[11];
  const float* W1 = (const float*)d_in[12]; const float* bf1 = (const float*)d_in[13];
  const float* W2 = (const float*)d_in[14]; const float* b2  = (const float*)d_in[15];
  const float* g2 = (const float*)d_in[16]; const float* be2 = (const float*)d_in[17];

  char* ws = (char*)d_ws;
  int*      flag  = (int*)     (ws + OFF_FLAG);
  float*    kmax2 = (float*)   (ws + OFF_FLAG + 64);
  unsigned* mw    = (unsigned*)(ws + OFF_MASKW);
  u16* xb    = (u16*)(ws + OFF_XB);
  u16* wqkvt = (u16*)(ws + OFF_WQKVT);
  u16* wot   = (u16*)(ws + OFF_WOT);
  u16* w1t   = (u16*)(ws + OFF_W1T);
  u16* w2t   = (u16*)(ws + OFF_W2T);
  u16* qw    = (u16*)(ws + OFF_QW);
  u16* kw    = (u16*)(ws + OFF_KW);
  u16* vt    = (u16*)(ws + OFF_VT);
  u16* ao    = (u16*)(ws + OFF_AO);

  k_detect<<<1, 256, 0, stream>>>((const unsigned*)msk, flag, kmax2);
  k_pack  <<<(T_*T_/32)/256, 256, 0, stream>>>(msk, flag, mw);
  k_conv_x<<<(M_*D_/4)/256, 256, 0, stream>>>(x, xb);
  k_conv_w<<<131072/256, 256, 0, stream>>>(Wq, Wk, Wv, Wo, W1, W2, wqkvt, wot, w1t, w2t);
  k_qkv   <<<M_/16, 256, 0, stream>>>(xb, wqkvt, bq, bk, bv, qw, kw, vt);
  k_knorm <<<(B_*H_)*16, 256, 0, stream>>>(kw, kmax2);
  k_attn14<<<(B_*H_)*(T_/64), 256, 0, stream>>>(qw, kw, vt, mw, kmax2, ao);
  k_tail  <<<M_/16, 256, 0, stream>>>(ao, wot, bo, x, g1, be1, w1t, bf1, w2t, b2, g2, be2, (float*)d_out);
}